// Round 26
// baseline (1033.575 us; speedup 1.0000x reference)
//
#include <hip/hip_runtime.h>
#include <cstddef>

#define Bsz 2
#define Tt  2048
#define HIDc 2048
#define Hh  16
#define Kc  128
#define Dc  2048
#define BT  (Bsz*Tt)
#define TS  4
#define FGBs 384   // padded fused fa|ga|beta row stride

typedef __attribute__((ext_vector_type(8))) __bf16 bf16x8;
typedef __attribute__((ext_vector_type(4))) __bf16 bf16x4;
typedef __attribute__((ext_vector_type(4))) float f32x4;

// ---------------------------------------------------------------------------
// epilogue modes: 0 none, 1 decay, 3 sigmoid-if-col>=256
// (mode 5 resolved to 1/0 per blockIdx.z before calls)
// ---------------------------------------------------------------------------
__device__ __forceinline__ float epilogue(float vacc, int c, int mode,
                                          const float* __restrict__ alog,
                                          const float* __restrict__ dtb) {
    if (mode == 1) {
        float z  = vacc + dtb[c];
        float sp = fmaxf(z, 0.f) + log1pf(expf(-fabsf(z)));
        return expf(-expf(alog[c >> 7]) * sp);
    } else if (mode == 3) {
        return (c >= 256) ? 1.f / (1.f + expf(-vacc)) : vacc;
    }
    return vacc;
}

// ---------------------------------------------------------------------------
// bf16 MFMA GEMM with z-batching: C[z] = A[z] @ Bw[z]^T.
// ---------------------------------------------------------------------------
__global__ __launch_bounds__(256) void gemm_bf16_mfma(
    const __bf16* __restrict__ AB, size_t az,
    const __bf16* __restrict__ BwB, size_t bz,
    float* __restrict__ CB, size_t cz, __bf16* __restrict__ C2,
    int M, int N, int K, int lda, int mode,
    const float* __restrict__ alog, const float* __restrict__ dtb)
{
    __shared__ __bf16 As[128 * 64];
    __shared__ __bf16 Bs[128 * 64];
    const __bf16* A = AB + (size_t)blockIdx.z * az;
    const __bf16* Bw = BwB + (size_t)blockIdx.z * bz;
    float* C = CB + (size_t)blockIdx.z * cz;
    if (mode == 5) mode = (blockIdx.z == 0) ? 1 : 0;
    const int tid = threadIdx.x;
    const int lane = tid & 63;
    const int wave = tid >> 6;
    const int wr = wave >> 1, wc = wave & 1;
    const int l15 = lane & 15, g = lane >> 4;
    const int row0 = blockIdx.y * 128, col0 = blockIdx.x * 128;

    f32x4 acc[4][4];
#pragma unroll
    for (int m = 0; m < 4; m++)
#pragma unroll
        for (int n = 0; n < 4; n++)
            acc[m][n] = (f32x4){0.f, 0.f, 0.f, 0.f};

    for (int k0 = 0; k0 < K; k0 += 64) {
        __syncthreads();
#pragma unroll
        for (int i = 0; i < 4; i++) {
            const int c = i * 256 + tid;
            const int row = c >> 3, kc = c & 7;
            const int scol = k0 + 8 * (kc ^ (row & 7));
            __builtin_amdgcn_global_load_lds(
                (const __attribute__((address_space(1))) void*)(A + (size_t)(row0 + row) * lda + scol),
                (__attribute__((address_space(3))) void*)(As + (size_t)(i * 256 + (tid & ~63)) * 8),
                16, 0, 0);
        }
#pragma unroll
        for (int i = 0; i < 4; i++) {
            const int c = i * 256 + tid;
            const int row = c >> 3, kc = c & 7;
            const int scol = k0 + 8 * (kc ^ (row & 7));
            __builtin_amdgcn_global_load_lds(
                (const __attribute__((address_space(1))) void*)(Bw + (size_t)(col0 + row) * K + scol),
                (__attribute__((address_space(3))) void*)(Bs + (size_t)(i * 256 + (tid & ~63)) * 8),
                16, 0, 0);
        }
        __syncthreads();
#pragma unroll
        for (int ks = 0; ks < 2; ks++) {
            bf16x8 af[4], bfr[4];
#pragma unroll
            for (int m = 0; m < 4; m++) {
                const int row = wr * 64 + m * 16 + l15;
                const int kc = ks * 4 + g;
                af[m] = *(const bf16x8*)(As + row * 64 + 8 * (kc ^ (row & 7)));
            }
#pragma unroll
            for (int n = 0; n < 4; n++) {
                const int col = wc * 64 + n * 16 + l15;
                const int kc = ks * 4 + g;
                bfr[n] = *(const bf16x8*)(Bs + col * 64 + 8 * (kc ^ (col & 7)));
            }
#pragma unroll
            for (int m = 0; m < 4; m++)
#pragma unroll
                for (int n = 0; n < 4; n++)
                    acc[m][n] = __builtin_amdgcn_mfma_f32_16x16x32_bf16(
                        af[m], bfr[n], acc[m][n], 0, 0, 0);
        }
    }
#pragma unroll
    for (int m = 0; m < 4; m++) {
        const int rbase = row0 + wr * 64 + m * 16 + g * 4;
#pragma unroll
        for (int n = 0; n < 4; n++) {
            const int col = col0 + wc * 64 + n * 16 + l15;
#pragma unroll
            for (int r = 0; r < 4; r++) {
                const float val = epilogue(acc[m][n][r], col, mode, alog, dtb);
                C[(size_t)(rbase + r) * N + col] = val;
                if (C2) C2[(size_t)(rbase + r) * N + col] = (__bf16)val;
            }
        }
    }
}

// f32 -> bf16 elementwise (4 per thread)
__global__ __launch_bounds__(256) void cvt_bf16(
    const float* __restrict__ in, __bf16* __restrict__ o)
{
    const int i = blockIdx.x * 256 + threadIdx.x;
    float4 v = *(const float4*)(in + (size_t)4 * i);
    bf16x4 r;
    r[0] = (__bf16)v.x; r[1] = (__bf16)v.y; r[2] = (__bf16)v.z; r[3] = (__bf16)v.w;
    *(bf16x4*)(o + (size_t)4 * i) = r;
}

// W[K,N] f32 -> WT[N,K] bf16 (single)
__global__ __launch_bounds__(256) void transpose_to_bf16(
    const float* __restrict__ W, __bf16* __restrict__ WT, int Kd, int N)
{
    __shared__ float tile[32][33];
    const int n0 = blockIdx.x * 32, k0 = blockIdx.y * 32;
    const int tx = threadIdx.x & 31, ty = threadIdx.x >> 5;
#pragma unroll
    for (int i = 0; i < 4; i++)
        tile[ty + 8 * i][tx] = W[(size_t)(k0 + ty + 8 * i) * N + n0 + tx];
    __syncthreads();
#pragma unroll
    for (int i = 0; i < 4; i++)
        WT[(size_t)(n0 + ty + 8 * i) * Kd + k0 + tx] = (__bf16)tile[tx][ty + 8 * i];
}

// z-batched weight transpose (up to 3 sources -> WTB[z])
__global__ __launch_bounds__(256) void transpose3_to_bf16(
    const float* __restrict__ W0, const float* __restrict__ W1,
    const float* __restrict__ W2, __bf16* __restrict__ WTB, size_t wz,
    int Kd, int N)
{
    __shared__ float tile[32][33];
    const float* W = (blockIdx.z == 0) ? W0 : (blockIdx.z == 1) ? W1 : W2;
    __bf16* WT = WTB + (size_t)blockIdx.z * wz;
    const int n0 = blockIdx.x * 32, k0 = blockIdx.y * 32;
    const int tx = threadIdx.x & 31, ty = threadIdx.x >> 5;
#pragma unroll
    for (int i = 0; i < 4; i++)
        tile[ty + 8 * i][tx] = W[(size_t)(k0 + ty + 8 * i) * N + n0 + tx];
    __syncthreads();
#pragma unroll
    for (int i = 0; i < 4; i++)
        WT[(size_t)(n0 + ty + 8 * i) * Kd + k0 + tx] = (__bf16)tile[tx][ty + 8 * i];
}

// pack transposed skinny weights: BcatT[c][k] (bf16, c<384, k<2048)
__global__ __launch_bounds__(256) void pack_fgbT(
    const float* __restrict__ Wfa, const float* __restrict__ Wga,
    const float* __restrict__ Wb, __bf16* __restrict__ BcatT)
{
    const int i = blockIdx.x * 256 + threadIdx.x;
    if (i >= FGBs * HIDc) return;
    const int c = i / HIDc, k = i % HIDc;
    float v = 0.f;
    if (c < 128)      v = Wfa[(size_t)k * 128 + c];
    else if (c < 256) v = Wga[(size_t)k * 128 + (c - 128)];
    else if (c < 272) v = Wb[(size_t)k * 16 + (c - 256)];
    BcatT[i] = (__bf16)v;
}

// ---------------------------------------------------------------------------
// causal depthwise conv (KC=4) + SiLU, optional l2norm over 128-group.
// ---------------------------------------------------------------------------
__global__ __launch_bounds__(128) void conv_silu_norm(
    const float* __restrict__ pre, const float* __restrict__ cw,
    const float* __restrict__ cb, float* __restrict__ out, int mode)
{
    const int bid = blockIdx.x;
    const int h = bid & (Hh - 1);
    const int bt = bid >> 4;
    const int t = bt & (Tt - 1);
    const int lane = threadIdx.x;
    const int col = h * Kc + lane;
    const float w0 = cw[col * 4 + 0], w1 = cw[col * 4 + 1];
    const float w2 = cw[col * 4 + 2], w3 = cw[col * 4 + 3];
    const float* bp = pre + (size_t)bt * Dc + col;
    float acc = cb[col] + w3 * bp[0];
    if (t >= 1) acc += w2 * bp[-Dc];
    if (t >= 2) acc += w1 * bp[-2 * Dc];
    if (t >= 3) acc += w0 * bp[-3 * Dc];
    float val = acc / (1.f + expf(-acc));   // silu
    if (mode) {
        float ss = val * val;
#pragma unroll
        for (int m = 1; m < 64; m <<= 1) ss += __shfl_xor(ss, m);
        __shared__ float p2[2];
        if ((lane & 63) == 0) p2[lane >> 6] = ss;
        __syncthreads();
        float tot = p2[0] + p2[1];
        float r = rsqrtf(tot + 1e-6f);
        val *= r;
        if (mode == 2) val *= 0.08838834764831845f;  // 128^-0.5
    }
    out[(size_t)bt * Dc + col] = val;
}

// ---------------------------------------------------------------------------
// cross-lane sum helpers (DPP + permlane16_swap), R14-verified.
// ---------------------------------------------------------------------------
template <int CTRL>
__device__ __forceinline__ float dpp_add(float v) {
    return __int_as_float(__builtin_amdgcn_update_dpp(
        0, __float_as_int(v), CTRL, 0xf, 0xf, true));
}

__device__ __forceinline__ float sum_x16(float v) {
#if __has_builtin(__builtin_amdgcn_permlane16_swap)
    auto r = __builtin_amdgcn_permlane16_swap(__float_as_uint(v), __float_as_uint(v),
                                              false, false);
    return __uint_as_float(r[0]) + __uint_as_float(r[1]);
#else
    return v + __shfl_xor(v, 16);
#endif
}

// sum over the 32 kq lanes of each half (strides 1,2,4,8 DPP; 16 permlane)
__device__ __forceinline__ void reduce3_32(float& a, float& b, float& c) {
    a += dpp_add<0xB1>(a);
    b += dpp_add<0xB1>(b);
    c += dpp_add<0xB1>(c);
    a += dpp_add<0x4E>(a);
    b += dpp_add<0x4E>(b);
    c += dpp_add<0x4E>(c);
    a += dpp_add<0x124>(a);
    b += dpp_add<0x124>(b);
    c += dpp_add<0x124>(c);
    a += dpp_add<0x128>(a);
    b += dpp_add<0x128>(b);
    c += dpp_add<0x128>(c);
    a = sum_x16(a);
    b = sum_x16(b);
    c = sum_x16(c);
}

// ---------------------------------------------------------------------------
// KDA step, 4 k-elems per lane (kq = lane&31 over 32 groups; vloc = lane>>5).
// Each 32-lane half holds the FULL k-range for its v (R14-verified layout).
// ---------------------------------------------------------------------------
__device__ __forceinline__ float kda_step(
    const float4 cq, const float4 ck, const float4 cd,
    float cv, float cbt, float S[4])
{
    S[0] *= cd.x;
    S[1] *= cd.y;
    S[2] *= cd.z;
    S[3] *= cd.w;
    float kv0 = 0.f, kv1 = 0.f, qs0 = 0.f, qs1 = 0.f, qk0 = 0.f, qk1 = 0.f;
    kv0 = fmaf(ck.x, S[0], kv0);
    kv1 = fmaf(ck.y, S[1], kv1);
    kv0 = fmaf(ck.z, S[2], kv0);
    kv1 = fmaf(ck.w, S[3], kv1);
    qs0 = fmaf(cq.x, S[0], qs0);
    qs1 = fmaf(cq.y, S[1], qs1);
    qs0 = fmaf(cq.z, S[2], qs0);
    qs1 = fmaf(cq.w, S[3], qs1);
    qk0 = fmaf(ck.x, cq.x, qk0);
    qk1 = fmaf(ck.y, cq.y, qk1);
    qk0 = fmaf(ck.z, cq.z, qk0);
    qk1 = fmaf(ck.w, cq.w, qk1);
    float kv = kv0 + kv1, qs = qs0 + qs1, qk = qk0 + qk1;
    reduce3_32(kv, qs, qk);
    float vd = (cv - kv) * cbt;
    float ov = fmaf(qk, vd, qs);
    S[0] = fmaf(ck.x, vd, S[0]);
    S[1] = fmaf(ck.y, vd, S[1]);
    S[2] = fmaf(ck.z, vd, S[2]);
    S[3] = fmaf(ck.w, vd, S[3]);
    return ov;
}

// compute TS steps from one staged LDS buffer (one-step register rotation)
__device__ __forceinline__ void kda_tile(
    const float (*sm)[TS * 128], const float* vm,
    const float* bm, float S[4], int kq, int vloc,
    float* __restrict__ op, int lane)
{
    float4 cq, ck, cd;
    float cv, cb;
    cq = *(const float4*)&sm[0][kq * 4];
    ck = *(const float4*)&sm[1][kq * 4];
    cd = *(const float4*)&sm[2][kq * 4];
    cv = vm[vloc];
    cb = bm[0];
#pragma unroll
    for (int t = 0; t < TS; ++t) {
        float4 nq, nk, nd;
        float nv = 0.f, nb = 0.f;
        if (t + 1 < TS) {
            nq = *(const float4*)&sm[0][(t + 1) * 128 + kq * 4];
            nk = *(const float4*)&sm[1][(t + 1) * 128 + kq * 4];
            nd = *(const float4*)&sm[2][(t + 1) * 128 + kq * 4];
            nv = vm[(t + 1) * 2 + vloc];
            nb = bm[t + 1];
        }
        const float ov = kda_step(cq, ck, cd, cv, cb, S);
        if ((lane & 31) == 0)
            op[(size_t)t * Dc + vloc] = ov;
        if (t + 1 < TS) {
            cq = nq; ck = nk; cd = nd; cv = nv; cb = nb;
        }
    }
}

// ---------------------------------------------------------------------------
// KDA gated delta-rule scan: v-chunk=2 layout (R14) + triple-buffered
// counted-vmcnt pipeline (R19).  Grid 2048, 1 wave/block, TS=4.
// LDS 18.6 KB -> 8 blocks/CU -> 2 waves/SIMD (R12-R25 had 1).
// Per-STAGE vmem = 8 (6 b128-lds + v + beta); stores/tile = 4.
// Steady wait vmcnt(12) = stage(t+2) 8 + stores 4; tail vmcnt(4).
// XCD-grouped decode: all 64 v-blocks of a (b,h) share bid%8.
// ---------------------------------------------------------------------------
__global__ __launch_bounds__(64, 2) void kda_scan_kernel(
    const float* __restrict__ q, const float* __restrict__ k,
    const float* __restrict__ v, const float* __restrict__ dec,
    const float* __restrict__ fgb, float* __restrict__ o)
{
    __shared__ float sA[3][TS * 128];
    __shared__ float sB[3][TS * 128];
    __shared__ float sC[3][TS * 128];
    __shared__ float vA[TS * 2], vB[TS * 2], vC[TS * 2];
    __shared__ float bA[TS], bB[TS], bC[TS];

    const int bid = blockIdx.x;
    const int r8 = bid & 7;
    const int s = bid >> 3;                 // 0..255
    const int bh = r8 + 8 * (s >> 6);       // bijective over [0,32)
    const int vc = s & 63;                  // v-chunk of 2
    const int h = bh & (Hh - 1);
    const int b = bh >> 4;
    const int lane = threadIdx.x;
    const int vloc = lane >> 5;
    const int kq = lane & 31;
    const size_t base = ((size_t)b * Tt) * Dc + h * Kc;
    const size_t bbase = ((size_t)b * Tt) * FGBs + 256 + h;

    float S[4];
#pragma unroll
    for (int i = 0; i < 4; i++) S[i] = 0.f;

    // staging: per matrix, chunk c = r*64 + lane (r=0..1);
    // t = 2r + (lane>>5), float4-col w = lane&31 (linear)
    const int s_t = lane >> 5;
    const int s_w = lane & 31;

#define STAGE(TILE, SM, VM, BM)                                                 \
    {                                                                           \
        _Pragma("unroll")                                                       \
        for (int r = 0; r < 2; r++) {                                           \
            const size_t rb = base + (size_t)((TILE) * TS + 2 * r + s_t) * Dc   \
                              + s_w * 4;                                        \
            __builtin_amdgcn_global_load_lds(                                   \
                (const __attribute__((address_space(1))) void*)(q + rb),        \
                (__attribute__((address_space(3))) void*)(&SM[0][r * 256]),     \
                16, 0, 0);                                                      \
            __builtin_amdgcn_global_load_lds(                                   \
                (const __attribute__((address_space(1))) void*)(k + rb),        \
                (__attribute__((address_space(3))) void*)(&SM[1][r * 256]),     \
                16, 0, 0);                                                      \
            __builtin_amdgcn_global_load_lds(                                   \
                (const __attribute__((address_space(1))) void*)(dec + rb),      \
                (__attribute__((address_space(3))) void*)(&SM[2][r * 256]),     \
                16, 0, 0);                                                      \
        }                                                                       \
        if (lane < 2 * TS)                                                      \
            __builtin_amdgcn_global_load_lds(                                   \
                (const __attribute__((address_space(1))) void*)(v + base        \
                    + (size_t)((TILE) * TS + (lane >> 1)) * Dc + vc * 2         \
                    + (lane & 1)),                                              \
                (__attribute__((address_space(3))) void*)(&VM[0]), 4, 0, 0);    \
        if (lane < TS)                                                          \
            __builtin_amdgcn_global_load_lds(                                   \
                (const __attribute__((address_space(1))) void*)(fgb + bbase     \
                    + (size_t)((TILE) * TS + lane) * FGBs),                     \
                (__attribute__((address_space(3))) void*)(&BM[0]), 4, 0, 0);    \
    }

    STAGE(0, sA, vA, bA);
    STAGE(1, sB, vB, bB);
    asm volatile("s_waitcnt vmcnt(8)" ::: "memory");   // buffer 0 ready
    __builtin_amdgcn_sched_barrier(0);

    const int NT = Tt / TS;   // 512
    int cur = 0, nx2 = 2;     // rotating buffer indices
    for (int tile = 0; tile < NT; ++tile) {
        if (tile + 2 < NT) {
            float (*sT)[TS * 128] = (nx2 == 0) ? sA : (nx2 == 1) ? sB : sC;
            float* vT = (nx2 == 0) ? vA : (nx2 == 1) ? vB : vC;
            float* bT = (nx2 == 0) ? bA : (nx2 == 1) ? bB : bC;
            STAGE(tile + 2, sT, vT, bT);
            __builtin_amdgcn_sched_barrier(0);
        }
        const float (*sm)[TS * 128] = (cur == 0) ? sA : (cur == 1) ? sB : sC;
        const float* vm = (cur == 0) ? vA : (cur == 1) ? vB : vC;
        const float* bm = (cur == 0) ? bA : (cur == 1) ? bB : bC;
        kda_tile(sm, vm, bm, S, kq, vloc,
                 o + base + (size_t)tile * TS * Dc + vc * 2, lane);
        if (tile + 2 < NT)
            asm volatile("s_waitcnt vmcnt(12)" ::: "memory");
        else
            asm volatile("s_waitcnt vmcnt(4)" ::: "memory");
        __builtin_amdgcn_sched_barrier(0);
        cur = (cur == 2) ? 0 : cur + 1;
        nx2 = (nx2 == 2) ? 0 : nx2 + 1;
    }
#undef STAGE
}

// ---------------------------------------------------------------------------
// gated head-wise RMSNorm -> bf16 output (feeds the Wo MFMA GEMM directly)
// ---------------------------------------------------------------------------
__global__ __launch_bounds__(128) void post_norm(
    const float* __restrict__ o, const float* __restrict__ gate,
    const float* __restrict__ onw, __bf16* __restrict__ og)
{
    const int bid = blockIdx.x;
    const int h = bid & (Hh - 1);
    const int bt = bid >> 4;
    const int lane = threadIdx.x;
    size_t idx = (size_t)bt * Dc + h * Kc + lane;
    float ov = o[idx];
    float ss = ov * ov;
#pragma unroll
    for (int m = 1; m < 64; m <<= 1) ss += __shfl_xor(ss, m);
    __shared__ float p2[2];
    if ((lane & 63) == 0) p2[lane >> 6] = ss;
    __syncthreads();
    float var = (p2[0] + p2[1]) * (1.f / 128.f);
    float r = rsqrtf(var + 1e-5f);
    float gt = gate[idx];
    og[idx] = (__bf16)(ov * r * onw[lane] * (1.f / (1.f + expf(-gt))));
}

// ---------------------------------------------------------------------------
extern "C" void kernel_launch(void* const* d_in, const int* in_sizes, int n_in,
                              void* d_out, int out_size, void* d_ws, size_t ws_size,
                              hipStream_t stream) {
    const float* x        = (const float*)d_in[0];
    const float* Wq       = (const float*)d_in[1];
    const float* Wk       = (const float*)d_in[2];
    const float* Wv       = (const float*)d_in[3];
    const float* conv_q_w = (const float*)d_in[4];
    const float* conv_q_b = (const float*)d_in[5];
    const float* conv_k_w = (const float*)d_in[6];
    const float* conv_k_b = (const float*)d_in[7];
    const float* conv_v_w = (const float*)d_in[8];
    const float* conv_v_b = (const float*)d_in[9];
    const float* Wfa      = (const float*)d_in[10];
    const float* Wfb      = (const float*)d_in[11];
    const float* A_log    = (const float*)d_in[12];
    const float* dt_bias  = (const float*)d_in[13];
    const float* Wb       = (const float*)d_in[14];
    const float* Wga      = (const float*)d_in[15];
    const float* Wgb      = (const float*)d_in[16];
    const float* o_norm_w = (const float*)d_in[17];
    const float* Wo       = (const float*)d_in[18];
    float* out = (float*)d_out;

    float* ws = (float*)d_ws;
    const size_t SZ = (size_t)BT * Dc;      // 8.39M floats
    float* bufA = ws + 0 * SZ;   // qpre -> k     (z=0 GEMM out)
    float* bufB = ws + 1 * SZ;   // kpre -> v     (z=1)
    float* bufC = ws + 2 * SZ;   // vpre -> o     (z=2)
    float* bufG = ws + 3 * SZ;   // decay         (merged GEMM z=0)
    float* bufI = ws + 4 * SZ;   // gate          (merged GEMM z=1, cz=SZ)
    float* bufQ = ws + 5 * SZ;   // q
    float* fgb  = ws + 6 * SZ;                          // BT*384 f32 (fa|ga|beta)
    __bf16* fgb16 = (__bf16*)(fgb + (size_t)BT * FGBs); // BT*384 bf16 mirror
    __bf16* xb    = fgb16 + (size_t)BT * FGBs;          // BT*Dc bf16 (x, later og)
    __bf16* wT3   = xb + SZ;                            // 3 x HIDc*Dc bf16
    __bf16* BcatT = wT3 + (size_t)3 * HIDc * Dc;        // 384*2048 bf16
    const size_t WZ = (size_t)HIDc * Dc;
    const size_t WZS = (size_t)Dc * Kc;                 // skinny weight slot

    dim3 blk(256);
    // 0: x -> bf16 ; pack transposed skinny weights
    cvt_bf16<<<dim3(SZ / 1024), blk, 0, stream>>>(x, xb);
    pack_fgbT<<<dim3((FGBs * HIDc + 255) / 256), blk, 0, stream>>>(Wfa, Wga, Wb, BcatT);
    // 1: Wq/Wk/Wv transposes in one z-batched dispatch
    dim3 tgrid3(Dc / 32, HIDc / 32, 3);
    transpose3_to_bf16<<<tgrid3, blk, 0, stream>>>(Wq, Wk, Wv, wT3, WZ, HIDc, Dc);
    // 2: q/k/v projections in one z-batched MFMA dispatch
    dim3 gbig3(Dc / 128, BT / 128, 3);
    gemm_bf16_mfma<<<gbig3, blk, 0, stream>>>(xb, 0, wT3, WZ, bufA, SZ, nullptr,
                                              BT, Dc, HIDc, HIDc, 0, nullptr, nullptr);
    // 3: fused skinny projection (K=2048, N=384, sigmoid on beta cols) ->
    //    f32 fgb + bf16 mirror
    dim3 gskin(FGBs / 128, BT / 128, 1);
    gemm_bf16_mfma<<<gskin, blk, 0, stream>>>(xb, 0, BcatT, 0, fgb, 0, fgb16,
                                              BT, FGBs, HIDc, HIDc, 3, nullptr, nullptr);
    // 4: Wfb/Wgb transposes (z=2 batched into wT3 slots of WZS)
    dim3 tskin2(Dc / 32, Kc / 32, 2);
    transpose3_to_bf16<<<tskin2, blk, 0, stream>>>(Wfb, Wgb, Wgb, wT3, WZS, Kc, Dc);
    // 5: decay+gate in one z=2 batched MFMA (az=128, mode 5: z0 decay, z1 none)
    dim3 gdg(Dc / 128, BT / 128, 2);
    gemm_bf16_mfma<<<gdg, blk, 0, stream>>>(fgb16, 128, wT3, WZS, bufG, SZ, nullptr,
                                            BT, Dc, Kc, FGBs, 5, A_log, dt_bias);
    // 6-8: conv + silu (+ l2norm)
    dim3 cblk(128);
    dim3 cgrid(BT * Hh);
    conv_silu_norm<<<cgrid, cblk, 0, stream>>>(bufA, conv_q_w, conv_q_b, bufQ, 2);
    conv_silu_norm<<<cgrid, cblk, 0, stream>>>(bufB, conv_k_w, conv_k_b, bufA, 1);
    conv_silu_norm<<<cgrid, cblk, 0, stream>>>(bufC, conv_v_w, conv_v_b, bufB, 0);
    // 9: scan  (q=bufQ, k=bufA, v=bufB, dec=bufG, beta in fgb -> o=bufC)
    kda_scan_kernel<<<dim3(2048), dim3(64), 0, stream>>>(bufQ, bufA, bufB, bufG, fgb, bufC);
    // 10: gated RMSNorm -> og (bf16, directly into xb)
    post_norm<<<cgrid, cblk, 0, stream>>>(bufC, bufI, o_norm_w, xb);
    // 11: out = og @ Wo (bf16 MFMA)
    dim3 tgrid(Dc / 32, HIDc / 32);
    transpose_to_bf16<<<tgrid, blk, 0, stream>>>(Wo, wT3, Dc, HIDc);
    dim3 gout(HIDc / 128, BT / 128, 1);
    gemm_bf16_mfma<<<gout, blk, 0, stream>>>(xb, 0, wT3, 0, out, 0, nullptr,
                                             BT, HIDc, Dc, Dc, 0, nullptr, nullptr);
}

// Round 27
// 907.814 us; speedup vs baseline: 1.1385x; 1.1385x over previous
//
#include <hip/hip_runtime.h>
#include <cstddef>

#define Bsz 2
#define Tt  2048
#define HIDc 2048
#define Hh  16
#define Kc  128
#define Dc  2048
#define BT  (Bsz*Tt)
#define TS  8
#define FGBs 384   // padded fused fa|ga|beta row stride

typedef __attribute__((ext_vector_type(8))) __bf16 bf16x8;
typedef __attribute__((ext_vector_type(4))) __bf16 bf16x4;
typedef __attribute__((ext_vector_type(4))) float f32x4;

// ---------------------------------------------------------------------------
// epilogue modes: 0 none, 1 decay, 3 sigmoid-if-col>=256
// (mode 5 resolved to 1/0 per blockIdx.z before calls)
// ---------------------------------------------------------------------------
__device__ __forceinline__ float epilogue(float vacc, int c, int mode,
                                          const float* __restrict__ alog,
                                          const float* __restrict__ dtb) {
    if (mode == 1) {
        float z  = vacc + dtb[c];
        float sp = fmaxf(z, 0.f) + log1pf(expf(-fabsf(z)));
        return expf(-expf(alog[c >> 7]) * sp);
    } else if (mode == 3) {
        return (c >= 256) ? 1.f / (1.f + expf(-vacc)) : vacc;
    }
    return vacc;
}

// ---------------------------------------------------------------------------
// bf16 MFMA GEMM with z-batching: C[z] = A[z] @ Bw[z]^T.
// A = A_base + z*az; Bw = Bw_base + z*bz; C = C_base + z*cz.
// 128x128 tile, 4 waves, BK=64.  f32 output C; optional bf16 mirror C2.
// mode 5: z==0 -> decay epilogue, z>0 -> none.
// ---------------------------------------------------------------------------
__global__ __launch_bounds__(256) void gemm_bf16_mfma(
    const __bf16* __restrict__ AB, size_t az,
    const __bf16* __restrict__ BwB, size_t bz,
    float* __restrict__ CB, size_t cz, __bf16* __restrict__ C2,
    int M, int N, int K, int lda, int mode,
    const float* __restrict__ alog, const float* __restrict__ dtb)
{
    __shared__ __bf16 As[128 * 64];
    __shared__ __bf16 Bs[128 * 64];
    const __bf16* A = AB + (size_t)blockIdx.z * az;
    const __bf16* Bw = BwB + (size_t)blockIdx.z * bz;
    float* C = CB + (size_t)blockIdx.z * cz;
    if (mode == 5) mode = (blockIdx.z == 0) ? 1 : 0;
    const int tid = threadIdx.x;
    const int lane = tid & 63;
    const int wave = tid >> 6;
    const int wr = wave >> 1, wc = wave & 1;
    const int l15 = lane & 15, g = lane >> 4;
    const int row0 = blockIdx.y * 128, col0 = blockIdx.x * 128;

    f32x4 acc[4][4];
#pragma unroll
    for (int m = 0; m < 4; m++)
#pragma unroll
        for (int n = 0; n < 4; n++)
            acc[m][n] = (f32x4){0.f, 0.f, 0.f, 0.f};

    for (int k0 = 0; k0 < K; k0 += 64) {
        __syncthreads();
#pragma unroll
        for (int i = 0; i < 4; i++) {
            const int c = i * 256 + tid;
            const int row = c >> 3, kc = c & 7;
            const int scol = k0 + 8 * (kc ^ (row & 7));
            __builtin_amdgcn_global_load_lds(
                (const __attribute__((address_space(1))) void*)(A + (size_t)(row0 + row) * lda + scol),
                (__attribute__((address_space(3))) void*)(As + (size_t)(i * 256 + (tid & ~63)) * 8),
                16, 0, 0);
        }
#pragma unroll
        for (int i = 0; i < 4; i++) {
            const int c = i * 256 + tid;
            const int row = c >> 3, kc = c & 7;
            const int scol = k0 + 8 * (kc ^ (row & 7));
            __builtin_amdgcn_global_load_lds(
                (const __attribute__((address_space(1))) void*)(Bw + (size_t)(col0 + row) * K + scol),
                (__attribute__((address_space(3))) void*)(Bs + (size_t)(i * 256 + (tid & ~63)) * 8),
                16, 0, 0);
        }
        __syncthreads();
#pragma unroll
        for (int ks = 0; ks < 2; ks++) {
            bf16x8 af[4], bfr[4];
#pragma unroll
            for (int m = 0; m < 4; m++) {
                const int row = wr * 64 + m * 16 + l15;
                const int kc = ks * 4 + g;
                af[m] = *(const bf16x8*)(As + row * 64 + 8 * (kc ^ (row & 7)));
            }
#pragma unroll
            for (int n = 0; n < 4; n++) {
                const int col = wc * 64 + n * 16 + l15;
                const int kc = ks * 4 + g;
                bfr[n] = *(const bf16x8*)(Bs + col * 64 + 8 * (kc ^ (col & 7)));
            }
#pragma unroll
            for (int m = 0; m < 4; m++)
#pragma unroll
                for (int n = 0; n < 4; n++)
                    acc[m][n] = __builtin_amdgcn_mfma_f32_16x16x32_bf16(
                        af[m], bfr[n], acc[m][n], 0, 0, 0);
        }
    }
#pragma unroll
    for (int m = 0; m < 4; m++) {
        const int rbase = row0 + wr * 64 + m * 16 + g * 4;
#pragma unroll
        for (int n = 0; n < 4; n++) {
            const int col = col0 + wc * 64 + n * 16 + l15;
#pragma unroll
            for (int r = 0; r < 4; r++) {
                const float val = epilogue(acc[m][n][r], col, mode, alog, dtb);
                C[(size_t)(rbase + r) * N + col] = val;
                if (C2) C2[(size_t)(rbase + r) * N + col] = (__bf16)val;
            }
        }
    }
}

// f32 -> bf16 elementwise (4 per thread)
__global__ __launch_bounds__(256) void cvt_bf16(
    const float* __restrict__ in, __bf16* __restrict__ o)
{
    const int i = blockIdx.x * 256 + threadIdx.x;
    float4 v = *(const float4*)(in + (size_t)4 * i);
    bf16x4 r;
    r[0] = (__bf16)v.x; r[1] = (__bf16)v.y; r[2] = (__bf16)v.z; r[3] = (__bf16)v.w;
    *(bf16x4*)(o + (size_t)4 * i) = r;
}

// W[K,N] f32 -> WT[N,K] bf16 (single)
__global__ __launch_bounds__(256) void transpose_to_bf16(
    const float* __restrict__ W, __bf16* __restrict__ WT, int Kd, int N)
{
    __shared__ float tile[32][33];
    const int n0 = blockIdx.x * 32, k0 = blockIdx.y * 32;
    const int tx = threadIdx.x & 31, ty = threadIdx.x >> 5;
#pragma unroll
    for (int i = 0; i < 4; i++)
        tile[ty + 8 * i][tx] = W[(size_t)(k0 + ty + 8 * i) * N + n0 + tx];
    __syncthreads();
#pragma unroll
    for (int i = 0; i < 4; i++)
        WT[(size_t)(n0 + ty + 8 * i) * Kd + k0 + tx] = (__bf16)tile[tx][ty + 8 * i];
}

// z-batched weight transpose (up to 3 sources -> WTB[z])
__global__ __launch_bounds__(256) void transpose3_to_bf16(
    const float* __restrict__ W0, const float* __restrict__ W1,
    const float* __restrict__ W2, __bf16* __restrict__ WTB, size_t wz,
    int Kd, int N)
{
    __shared__ float tile[32][33];
    const float* W = (blockIdx.z == 0) ? W0 : (blockIdx.z == 1) ? W1 : W2;
    __bf16* WT = WTB + (size_t)blockIdx.z * wz;
    const int n0 = blockIdx.x * 32, k0 = blockIdx.y * 32;
    const int tx = threadIdx.x & 31, ty = threadIdx.x >> 5;
#pragma unroll
    for (int i = 0; i < 4; i++)
        tile[ty + 8 * i][tx] = W[(size_t)(k0 + ty + 8 * i) * N + n0 + tx];
    __syncthreads();
#pragma unroll
    for (int i = 0; i < 4; i++)
        WT[(size_t)(n0 + ty + 8 * i) * Kd + k0 + tx] = (__bf16)tile[tx][ty + 8 * i];
}

// pack transposed skinny weights: BcatT[c][k] (bf16, c<384, k<2048)
__global__ __launch_bounds__(256) void pack_fgbT(
    const float* __restrict__ Wfa, const float* __restrict__ Wga,
    const float* __restrict__ Wb, __bf16* __restrict__ BcatT)
{
    const int i = blockIdx.x * 256 + threadIdx.x;
    if (i >= FGBs * HIDc) return;
    const int c = i / HIDc, k = i % HIDc;
    float v = 0.f;
    if (c < 128)      v = Wfa[(size_t)k * 128 + c];
    else if (c < 256) v = Wga[(size_t)k * 128 + (c - 128)];
    else if (c < 272) v = Wb[(size_t)k * 16 + (c - 256)];
    BcatT[i] = (__bf16)v;
}

// ---------------------------------------------------------------------------
// causal depthwise conv (KC=4) + SiLU, optional l2norm over 128-group.
// ---------------------------------------------------------------------------
__global__ __launch_bounds__(128) void conv_silu_norm(
    const float* __restrict__ pre, const float* __restrict__ cw,
    const float* __restrict__ cb, float* __restrict__ out, int mode)
{
    const int bid = blockIdx.x;
    const int h = bid & (Hh - 1);
    const int bt = bid >> 4;
    const int t = bt & (Tt - 1);
    const int lane = threadIdx.x;
    const int col = h * Kc + lane;
    const float w0 = cw[col * 4 + 0], w1 = cw[col * 4 + 1];
    const float w2 = cw[col * 4 + 2], w3 = cw[col * 4 + 3];
    const float* bp = pre + (size_t)bt * Dc + col;
    float acc = cb[col] + w3 * bp[0];
    if (t >= 1) acc += w2 * bp[-Dc];
    if (t >= 2) acc += w1 * bp[-2 * Dc];
    if (t >= 3) acc += w0 * bp[-3 * Dc];
    float val = acc / (1.f + expf(-acc));   // silu
    if (mode) {
        float ss = val * val;
#pragma unroll
        for (int m = 1; m < 64; m <<= 1) ss += __shfl_xor(ss, m);
        __shared__ float p2[2];
        if ((lane & 63) == 0) p2[lane >> 6] = ss;
        __syncthreads();
        float tot = p2[0] + p2[1];
        float r = rsqrtf(tot + 1e-6f);
        val *= r;
        if (mode == 2) val *= 0.08838834764831845f;  // 128^-0.5
    }
    out[(size_t)bt * Dc + col] = val;
}

// ---------------------------------------------------------------------------
// DPP helpers: sum over lane strides 1,2,4,8 within each 16-lane row.
// ---------------------------------------------------------------------------
template <int CTRL>
__device__ __forceinline__ float dpp_add(float v) {
    return __int_as_float(__builtin_amdgcn_update_dpp(
        0, __float_as_int(v), CTRL, 0xf, 0xf, true));
}

__device__ __forceinline__ void reduce3_row(float& a, float& b, float& c) {
    a += dpp_add<0xB1>(a);
    b += dpp_add<0xB1>(b);
    c += dpp_add<0xB1>(c);
    a += dpp_add<0x4E>(a);
    b += dpp_add<0x4E>(b);
    c += dpp_add<0x4E>(c);
    a += dpp_add<0x124>(a);
    b += dpp_add<0x124>(b);
    c += dpp_add<0x124>(c);
    a += dpp_add<0x128>(a);
    b += dpp_add<0x128>(b);
    c += dpp_add<0x128>(c);
}

// ---------------------------------------------------------------------------
// KDA step, 8 k-elems per lane.
// ---------------------------------------------------------------------------
__device__ __forceinline__ float kda_step(
    const float4 cq[2], const float4 ck[2], const float4 cd[2],
    float cv, float cbt, float S[8])
{
    float kv0 = 0.f, kv1 = 0.f, qs0 = 0.f, qs1 = 0.f, qk0 = 0.f, qk1 = 0.f;
#pragma unroll
    for (int i = 0; i < 2; i++) {
        S[4 * i + 0] *= cd[i].x;
        S[4 * i + 1] *= cd[i].y;
        S[4 * i + 2] *= cd[i].z;
        S[4 * i + 3] *= cd[i].w;
        kv0 = fmaf(ck[i].x, S[4 * i + 0], kv0);
        kv1 = fmaf(ck[i].y, S[4 * i + 1], kv1);
        kv0 = fmaf(ck[i].z, S[4 * i + 2], kv0);
        kv1 = fmaf(ck[i].w, S[4 * i + 3], kv1);
        qs0 = fmaf(cq[i].x, S[4 * i + 0], qs0);
        qs1 = fmaf(cq[i].y, S[4 * i + 1], qs1);
        qs0 = fmaf(cq[i].z, S[4 * i + 2], qs0);
        qs1 = fmaf(cq[i].w, S[4 * i + 3], qs1);
        qk0 = fmaf(ck[i].x, cq[i].x, qk0);
        qk1 = fmaf(ck[i].y, cq[i].y, qk1);
        qk0 = fmaf(ck[i].z, cq[i].z, qk0);
        qk1 = fmaf(ck[i].w, cq[i].w, qk1);
    }
    float kv = kv0 + kv1, qs = qs0 + qs1, qk = qk0 + qk1;
    reduce3_row(kv, qs, qk);
    float vd = (cv - kv) * cbt;
    float ov = fmaf(qk, vd, qs);
#pragma unroll
    for (int i = 0; i < 2; i++) {
        S[4 * i + 0] = fmaf(ck[i].x, vd, S[4 * i + 0]);
        S[4 * i + 1] = fmaf(ck[i].y, vd, S[4 * i + 1]);
        S[4 * i + 2] = fmaf(ck[i].z, vd, S[4 * i + 2]);
        S[4 * i + 3] = fmaf(ck[i].w, vd, S[4 * i + 3]);
    }
    return ov;
}

// compute TS steps from one staged LDS buffer (one-step register rotation).
// Slot rotation (R24, conflict-free): lane owns float4 slots (2kq+i+vloc)&31.
__device__ __forceinline__ void kda_tile(
    const float (*sm)[TS * 128], const float* vm,
    const float* bm, float S[8], int sl0, int sl1, int vloc,
    float* __restrict__ op, int lane)
{
    float4 cq[2], ck[2], cd[2];
    float cv, cb;
    cq[0] = *(const float4*)&sm[0][sl0];
    ck[0] = *(const float4*)&sm[1][sl0];
    cd[0] = *(const float4*)&sm[2][sl0];
    cq[1] = *(const float4*)&sm[0][sl1];
    ck[1] = *(const float4*)&sm[1][sl1];
    cd[1] = *(const float4*)&sm[2][sl1];
    cv = vm[vloc];
    cb = bm[0];
#pragma unroll
    for (int t = 0; t < TS; ++t) {
        float4 nq[2], nk[2], nd[2];
        float nv = 0.f, nb = 0.f;
        if (t + 1 < TS) {
            nq[0] = *(const float4*)&sm[0][(t + 1) * 128 + sl0];
            nk[0] = *(const float4*)&sm[1][(t + 1) * 128 + sl0];
            nd[0] = *(const float4*)&sm[2][(t + 1) * 128 + sl0];
            nq[1] = *(const float4*)&sm[0][(t + 1) * 128 + sl1];
            nk[1] = *(const float4*)&sm[1][(t + 1) * 128 + sl1];
            nd[1] = *(const float4*)&sm[2][(t + 1) * 128 + sl1];
            nv = vm[(t + 1) * 4 + vloc];
            nb = bm[t + 1];
        }
        const float ov = kda_step(cq, ck, cd, cv, cb, S);
        if ((lane & 15) == 0)
            op[(size_t)t * Dc + vloc] = ov;
        if (t + 1 < TS) {
#pragma unroll
            for (int i = 0; i < 2; i++) { cq[i] = nq[i]; ck[i] = nk[i]; cd[i] = nd[i]; }
            cv = nv; cb = nb;
        }
    }
}

// ---------------------------------------------------------------------------
// KDA gated delta-rule scan: TRIPLE-buffered global_load_lds staging with
// COUNTED vmcnt (steady-state vmcnt(22)).  Grid 1024, 1 wave/block.
// Rotating buffer counters (no % in loop).  beta f32 from fgb (stride FGBs).
// ---------------------------------------------------------------------------
__global__ __launch_bounds__(64, 2) void kda_scan_kernel(
    const float* __restrict__ q, const float* __restrict__ k,
    const float* __restrict__ v, const float* __restrict__ dec,
    const float* __restrict__ fgb, float* __restrict__ o)
{
    __shared__ float sA[3][TS * 128];
    __shared__ float sB[3][TS * 128];
    __shared__ float sC[3][TS * 128];
    __shared__ float vA[TS * 4], vB[TS * 4], vC[TS * 4];
    __shared__ float bA[TS], bB[TS], bC[TS];

    const int bid = blockIdx.x;
    const int r8 = bid & 7;
    const int s = bid >> 3;
    const int bh = r8 + 8 * (s >> 5);
    const int vc = s & 31;
    const int h = bh & (Hh - 1);
    const int b = bh >> 4;
    const int lane = threadIdx.x;
    const int vloc = lane >> 4;
    const int kq = lane & 15;
    const int sl0 = ((kq * 2 + 0 + vloc) & 31) * 4;
    const int sl1 = ((kq * 2 + 1 + vloc) & 31) * 4;
    const size_t base = ((size_t)b * Tt) * Dc + h * Kc;
    const size_t bbase = ((size_t)b * Tt) * FGBs + 256 + h;

    float S[8];
#pragma unroll
    for (int i = 0; i < 8; i++) S[i] = 0.f;

    const int s_t = lane >> 5;
    const int s_w = lane & 31;

#define STAGE(TILE, SM, VM, BM)                                                 \
    {                                                                           \
        _Pragma("unroll")                                                       \
        for (int r = 0; r < 4; r++) {                                           \
            const size_t rb = base + (size_t)((TILE) * TS + 2 * r + s_t) * Dc   \
                              + s_w * 4;                                        \
            __builtin_amdgcn_global_load_lds(                                   \
                (const __attribute__((address_space(1))) void*)(q + rb),        \
                (__attribute__((address_space(3))) void*)(&SM[0][r * 256]),     \
                16, 0, 0);                                                      \
            __builtin_amdgcn_global_load_lds(                                   \
                (const __attribute__((address_space(1))) void*)(k + rb),        \
                (__attribute__((address_space(3))) void*)(&SM[1][r * 256]),     \
                16, 0, 0);                                                      \
            __builtin_amdgcn_global_load_lds(                                   \
                (const __attribute__((address_space(1))) void*)(dec + rb),      \
                (__attribute__((address_space(3))) void*)(&SM[2][r * 256]),     \
                16, 0, 0);                                                      \
        }                                                                       \
        if (lane < 32)                                                          \
            __builtin_amdgcn_global_load_lds(                                   \
                (const __attribute__((address_space(1))) void*)(v + base        \
                    + (size_t)((TILE) * TS + (lane >> 2)) * Dc + vc * 4         \
                    + (lane & 3)),                                              \
                (__attribute__((address_space(3))) void*)(&VM[0]), 4, 0, 0);    \
        if (lane < TS)                                                          \
            __builtin_amdgcn_global_load_lds(                                   \
                (const __attribute__((address_space(1))) void*)(fgb + bbase     \
                    + (size_t)((TILE) * TS + lane) * FGBs),                     \
                (__attribute__((address_space(3))) void*)(&BM[0]), 4, 0, 0);    \
    }

    STAGE(0, sA, vA, bA);
    STAGE(1, sB, vB, bB);
    asm volatile("s_waitcnt vmcnt(14)" ::: "memory");
    __builtin_amdgcn_sched_barrier(0);

    const int NT = Tt / TS;   // 256
    int cur = 0, nx2 = 2;     // rotating buffer indices (no % in loop)
    for (int tile = 0; tile < NT; ++tile) {
        if (tile + 2 < NT) {
            float (*sT)[TS * 128] = (nx2 == 0) ? sA : (nx2 == 1) ? sB : sC;
            float* vT = (nx2 == 0) ? vA : (nx2 == 1) ? vB : vC;
            float* bT = (nx2 == 0) ? bA : (nx2 == 1) ? bB : bC;
            STAGE(tile + 2, sT, vT, bT);
            __builtin_amdgcn_sched_barrier(0);
        }
        const float (*sm)[TS * 128] = (cur == 0) ? sA : (cur == 1) ? sB : sC;
        const float* vm = (cur == 0) ? vA : (cur == 1) ? vB : vC;
        const float* bm = (cur == 0) ? bA : (cur == 1) ? bB : bC;
        kda_tile(sm, vm, bm, S, sl0, sl1, vloc,
                 o + base + (size_t)tile * TS * Dc + vc * 4, lane);
        if (tile + 2 < NT)
            asm volatile("s_waitcnt vmcnt(22)" ::: "memory");
        else
            asm volatile("s_waitcnt vmcnt(8)" ::: "memory");
        __builtin_amdgcn_sched_barrier(0);
        cur = (cur == 2) ? 0 : cur + 1;
        nx2 = (nx2 == 2) ? 0 : nx2 + 1;
    }
#undef STAGE
}

// ---------------------------------------------------------------------------
// gated head-wise RMSNorm -> bf16 output (feeds the Wo MFMA GEMM directly)
// ---------------------------------------------------------------------------
__global__ __launch_bounds__(128) void post_norm(
    const float* __restrict__ o, const float* __restrict__ gate,
    const float* __restrict__ onw, __bf16* __restrict__ og)
{
    const int bid = blockIdx.x;
    const int h = bid & (Hh - 1);
    const int bt = bid >> 4;
    const int lane = threadIdx.x;
    size_t idx = (size_t)bt * Dc + h * Kc + lane;
    float ov = o[idx];
    float ss = ov * ov;
#pragma unroll
    for (int m = 1; m < 64; m <<= 1) ss += __shfl_xor(ss, m);
    __shared__ float p2[2];
    if ((lane & 63) == 0) p2[lane >> 6] = ss;
    __syncthreads();
    float var = (p2[0] + p2[1]) * (1.f / 128.f);
    float r = rsqrtf(var + 1e-5f);
    float gt = gate[idx];
    og[idx] = (__bf16)(ov * r * onw[lane] * (1.f / (1.f + expf(-gt))));
}

// ---------------------------------------------------------------------------
extern "C" void kernel_launch(void* const* d_in, const int* in_sizes, int n_in,
                              void* d_out, int out_size, void* d_ws, size_t ws_size,
                              hipStream_t stream) {
    const float* x        = (const float*)d_in[0];
    const float* Wq       = (const float*)d_in[1];
    const float* Wk       = (const float*)d_in[2];
    const float* Wv       = (const float*)d_in[3];
    const float* conv_q_w = (const float*)d_in[4];
    const float* conv_q_b = (const float*)d_in[5];
    const float* conv_k_w = (const float*)d_in[6];
    const float* conv_k_b = (const float*)d_in[7];
    const float* conv_v_w = (const float*)d_in[8];
    const float* conv_v_b = (const float*)d_in[9];
    const float* Wfa      = (const float*)d_in[10];
    const float* Wfb      = (const float*)d_in[11];
    const float* A_log    = (const float*)d_in[12];
    const float* dt_bias  = (const float*)d_in[13];
    const float* Wb       = (const float*)d_in[14];
    const float* Wga      = (const float*)d_in[15];
    const float* Wgb      = (const float*)d_in[16];
    const float* o_norm_w = (const float*)d_in[17];
    const float* Wo       = (const float*)d_in[18];
    float* out = (float*)d_out;

    float* ws = (float*)d_ws;
    const size_t SZ = (size_t)BT * Dc;      // 8.39M floats
    float* bufA = ws + 0 * SZ;   // qpre -> k     (z=0 GEMM out)
    float* bufB = ws + 1 * SZ;   // kpre -> v     (z=1)
    float* bufC = ws + 2 * SZ;   // vpre -> o     (z=2)
    float* bufG = ws + 3 * SZ;   // decay         (merged GEMM z=0)
    float* bufI = ws + 4 * SZ;   // gate          (merged GEMM z=1, cz=SZ)
    float* bufQ = ws + 5 * SZ;   // q
    float* fgb  = ws + 6 * SZ;                          // BT*384 f32 (fa|ga|beta)
    __bf16* fgb16 = (__bf16*)(fgb + (size_t)BT * FGBs); // BT*384 bf16 mirror
    __bf16* xb    = fgb16 + (size_t)BT * FGBs;          // BT*Dc bf16 (x, later og)
    __bf16* wT3   = xb + SZ;                            // 3 x HIDc*Dc bf16
    __bf16* BcatT = wT3 + (size_t)3 * HIDc * Dc;        // 384*2048 bf16
    const size_t WZ = (size_t)HIDc * Dc;
    const size_t WZS = (size_t)Dc * Kc;                 // skinny weight slot

    dim3 blk(256);
    // 0: x -> bf16 ; pack transposed skinny weights
    cvt_bf16<<<dim3(SZ / 1024), blk, 0, stream>>>(x, xb);
    pack_fgbT<<<dim3((FGBs * HIDc + 255) / 256), blk, 0, stream>>>(Wfa, Wga, Wb, BcatT);
    // 1: Wq/Wk/Wv transposes in one z-batched dispatch
    dim3 tgrid3(Dc / 32, HIDc / 32, 3);
    transpose3_to_bf16<<<tgrid3, blk, 0, stream>>>(Wq, Wk, Wv, wT3, WZ, HIDc, Dc);
    // 2: q/k/v projections in one z-batched MFMA dispatch
    dim3 gbig3(Dc / 128, BT / 128, 3);
    gemm_bf16_mfma<<<gbig3, blk, 0, stream>>>(xb, 0, wT3, WZ, bufA, SZ, nullptr,
                                              BT, Dc, HIDc, HIDc, 0, nullptr, nullptr);
    // 3: fused skinny projection (K=2048, N=384, sigmoid on beta cols) ->
    //    f32 fgb + bf16 mirror
    dim3 gskin(FGBs / 128, BT / 128, 1);
    gemm_bf16_mfma<<<gskin, blk, 0, stream>>>(xb, 0, BcatT, 0, fgb, 0, fgb16,
                                              BT, FGBs, HIDc, HIDc, 3, nullptr, nullptr);
    // 4: Wfb/Wgb transposes (z=2 batched into wT3 slots of WZS)
    dim3 tskin2(Dc / 32, Kc / 32, 2);
    transpose3_to_bf16<<<tskin2, blk, 0, stream>>>(Wfb, Wgb, Wgb, wT3, WZS, Kc, Dc);
    // 5: decay+gate in one z=2 batched MFMA (az=128, mode 5: z0 decay, z1 none)
    dim3 gdg(Dc / 128, BT / 128, 2);
    gemm_bf16_mfma<<<gdg, blk, 0, stream>>>(fgb16, 128, wT3, WZS, bufG, SZ, nullptr,
                                            BT, Dc, Kc, FGBs, 5, A_log, dt_bias);
    // 6-8: conv + silu (+ l2norm)
    dim3 cblk(128);
    dim3 cgrid(BT * Hh);
    conv_silu_norm<<<cgrid, cblk, 0, stream>>>(bufA, conv_q_w, conv_q_b, bufQ, 2);
    conv_silu_norm<<<cgrid, cblk, 0, stream>>>(bufB, conv_k_w, conv_k_b, bufA, 1);
    conv_silu_norm<<<cgrid, cblk, 0, stream>>>(bufC, conv_v_w, conv_v_b, bufB, 0);
    // 9: scan  (q=bufQ, k=bufA, v=bufB, dec=bufG, beta in fgb -> o=bufC)
    kda_scan_kernel<<<dim3(1024), dim3(64), 0, stream>>>(bufQ, bufA, bufB, bufG, fgb, bufC);
    // 10: gated RMSNorm -> og (bf16, directly into xb)
    post_norm<<<cgrid, cblk, 0, stream>>>(bufC, bufI, o_norm_w, xb);
    // 11: out = og @ Wo (bf16 MFMA)
    dim3 tgrid(Dc / 32, HIDc / 32);
    transpose_to_bf16<<<tgrid, blk, 0, stream>>>(Wo, wT3, Dc, HIDc);
    dim3 gout(HIDc / 128, BT / 128, 1);
    gemm_bf16_mfma<<<gout, blk, 0, stream>>>(xb, 0, wT3, 0, out, 0, nullptr,
                                             BT, HIDc, Dc, Dc, 0, nullptr, nullptr);
}